// Round 1
// baseline (1113.891 us; speedup 1.0000x reference)
//
#include <hip/hip_runtime.h>

#define THREADS 256

__global__ void deg_kernel(const int* __restrict__ dst, float* __restrict__ deg, int E) {
    int e = blockIdx.x * blockDim.x + threadIdx.x;
    if (e < E) atomicAdd(&deg[dst[e]], 1.0f);
}

__global__ void rsqrt_kernel(float* deg, int N) {
    int i = blockIdx.x * blockDim.x + threadIdx.x;
    if (i < N) deg[i] = rsqrtf(deg[i] + 1.0f);  // +1 = self-loop
}

// Y[M,64] = X[M,K] @ W[K,64], fp32. One thread per (row, col); W staged in LDS.
template<int K>
__global__ void gemm_kernel(const float* __restrict__ X, const float* __restrict__ W,
                            float* __restrict__ Y, int M) {
    __shared__ float w[K * 64];
    int tid = threadIdx.x;
    for (int i = tid; i < K * 64; i += THREADS) w[i] = W[i];
    __syncthreads();
    int row = blockIdx.x * 4 + (tid >> 6);
    int col = tid & 63;
    if (row >= M) return;
    const float* xr = X + (size_t)row * K;
    float acc = 0.f;
    #pragma unroll
    for (int k = 0; k < K; ++k) acc = fmaf(xr[k], w[k * 64 + col], acc);
    Y[(size_t)row * 64 + col] = acc;
}

// One 64-lane wave per edge (edges E.. are self-loops). Lane f handles feature f.
__global__ void scatter_kernel(const float* __restrict__ h, const int* __restrict__ src,
                               const int* __restrict__ dst, const float* __restrict__ dis,
                               float* __restrict__ agg, int E, int N) {
    long long idx = (long long)blockIdx.x * blockDim.x + threadIdx.x;
    int e = (int)(idx >> 6);
    int f = (int)(idx & 63);
    if (e >= E + N) return;
    int s, d;
    if (e < E) { s = src[e]; d = dst[e]; } else { s = e - E; d = s; }
    float norm = dis[s] * dis[d];
    atomicAdd(&agg[(size_t)d * 64 + f], h[(size_t)s * 64 + f] * norm);
}

__global__ void bias_relu_kernel(float* __restrict__ buf, const float* __restrict__ b,
                                 long long total) {
    long long i = (long long)blockIdx.x * blockDim.x + threadIdx.x;
    if (i < total) {
        float v = buf[i] + b[(int)(i & 63)];
        buf[i] = v > 0.f ? v : 0.f;
    }
}

// One wave per pair: out[p] = dot(h[p0], Wh[0:64]) + dot(h[p1], Wh[64:128]) + bh
__global__ void head_kernel(const float* __restrict__ h, const int* __restrict__ pairs,
                            const float* __restrict__ Wh, const float* __restrict__ bh,
                            float* __restrict__ out, int P) {
    long long idx = (long long)blockIdx.x * blockDim.x + threadIdx.x;
    int p = (int)(idx >> 6);
    int lane = threadIdx.x & 63;
    if (p >= P) return;
    int p0 = pairs[2 * (size_t)p];
    int p1 = pairs[2 * (size_t)p + 1];
    float v = h[(size_t)p0 * 64 + lane] * Wh[lane]
            + h[(size_t)p1 * 64 + lane] * Wh[64 + lane];
    #pragma unroll
    for (int off = 32; off > 0; off >>= 1) v += __shfl_down(v, off);
    if (lane == 0) out[p] = v + bh[0];
}

extern "C" void kernel_launch(void* const* d_in, const int* in_sizes, int n_in,
                              void* d_out, int out_size, void* d_ws, size_t ws_size,
                              hipStream_t stream) {
    const float* x     = (const float*)d_in[0];
    const int*   ei    = (const int*)d_in[1];   // [2,E]: row0=src, row1=dst
    const int*   pairs = (const int*)d_in[3];   // [P,2]
    const float* W1    = (const float*)d_in[4];
    const float* b1    = (const float*)d_in[5];
    const float* W2    = (const float*)d_in[6];
    const float* b2    = (const float*)d_in[7];
    const float* Wh    = (const float*)d_in[8];
    const float* bh    = (const float*)d_in[9];

    const int N = in_sizes[0] / 128;
    const int E = in_sizes[1] / 2;
    const int P = in_sizes[3] / 2;
    const int* srcArr = ei;
    const int* dstArr = ei + E;

    char* ws = (char*)d_ws;
    size_t off = 0;
    float* deg = (float*)(ws + off);                      // N floats -> becomes deg_isqrt
    off += (((size_t)N * 4) + 511) & ~(size_t)511;
    float* bufA = (float*)(ws + off);                     // N*64 floats
    off += (((size_t)N * 64 * 4) + 511) & ~(size_t)511;
    float* bufB = (float*)(ws + off);                     // N*64 floats

    const size_t feat_total = (size_t)N * 64;
    const size_t edge_threads = (size_t)(E + N) * 64;

    // degree -> deg_isqrt
    hipMemsetAsync(deg, 0, (size_t)N * 4, stream);
    deg_kernel<<<(E + THREADS - 1) / THREADS, THREADS, 0, stream>>>(dstArr, deg, E);
    rsqrt_kernel<<<(N + THREADS - 1) / THREADS, THREADS, 0, stream>>>(deg, N);

    // layer 1
    gemm_kernel<128><<<(N + 3) / 4, THREADS, 0, stream>>>(x, W1, bufA, N);
    hipMemsetAsync(bufB, 0, feat_total * 4, stream);
    scatter_kernel<<<(unsigned)((edge_threads + THREADS - 1) / THREADS), THREADS, 0, stream>>>(
        bufA, srcArr, dstArr, deg, bufB, E, N);
    bias_relu_kernel<<<(unsigned)((feat_total + THREADS - 1) / THREADS), THREADS, 0, stream>>>(
        bufB, b1, (long long)feat_total);

    // layer 2
    gemm_kernel<64><<<(N + 3) / 4, THREADS, 0, stream>>>(bufB, W2, bufA, N);
    hipMemsetAsync(bufB, 0, feat_total * 4, stream);
    scatter_kernel<<<(unsigned)((edge_threads + THREADS - 1) / THREADS), THREADS, 0, stream>>>(
        bufA, srcArr, dstArr, deg, bufB, E, N);
    bias_relu_kernel<<<(unsigned)((feat_total + THREADS - 1) / THREADS), THREADS, 0, stream>>>(
        bufB, b2, (long long)feat_total);

    // head
    head_kernel<<<(unsigned)(((size_t)P * 64 + THREADS - 1) / THREADS), THREADS, 0, stream>>>(
        bufB, pairs, Wh, bh, (float*)d_out, P);
}

// Round 2
// 580.158 us; speedup vs baseline: 1.9200x; 1.9200x over previous
//
#include <hip/hip_runtime.h>

#define THREADS 256

// ---------------- CSR build ----------------

__global__ void hist_kernel(const int* __restrict__ dst, int* __restrict__ cnt, int E) {
    int e = blockIdx.x * blockDim.x + threadIdx.x;
    if (e < E) atomicAdd(&cnt[dst[e]], 1);
}

__global__ void dis_kernel(const int* __restrict__ cnt, float* __restrict__ dis, int N) {
    int i = blockIdx.x * blockDim.x + threadIdx.x;
    if (i < N) dis[i] = rsqrtf((float)cnt[i] + 1.0f);  // +1 self-loop
}

// block-local inclusive scan of cnt -> rowptr[i+1]; block totals -> bsum[b]
__global__ void scan_block_kernel(const int* __restrict__ cnt, int* __restrict__ rowptr,
                                  int* __restrict__ bsum, int N) {
    __shared__ int sh[1024];
    int t = threadIdx.x;
    int i = blockIdx.x * 1024 + t;
    sh[t] = (i < N) ? cnt[i] : 0;
    __syncthreads();
    for (int off = 1; off < 1024; off <<= 1) {
        int add = (t >= off) ? sh[t - off] : 0;
        __syncthreads();
        sh[t] += add;
        __syncthreads();
    }
    if (i < N) rowptr[i + 1] = sh[t];
    if (t == 1023) bsum[blockIdx.x] = sh[t];
}

// single-block exclusive scan of bsum (nb <= 1024)
__global__ void scan_partials_kernel(int* __restrict__ bsum, int nb) {
    __shared__ int sh[1024];
    int t = threadIdx.x;
    int v = (t < nb) ? bsum[t] : 0;
    sh[t] = v;
    __syncthreads();
    for (int off = 1; off < 1024; off <<= 1) {
        int add = (t >= off) ? sh[t - off] : 0;
        __syncthreads();
        sh[t] += add;
        __syncthreads();
    }
    if (t < nb) bsum[t] = sh[t] - v;  // exclusive
}

__global__ void scan_add_kernel(int* __restrict__ rowptr, const int* __restrict__ bsum, int N) {
    int i = blockIdx.x * blockDim.x + threadIdx.x;
    if (i < N) {
        rowptr[i + 1] += bsum[i >> 10];
        if (i == 0) rowptr[0] = 0;
    }
}

__global__ void fill_kernel(const int* __restrict__ src, const int* __restrict__ dst,
                            const int* __restrict__ rowptr, int* __restrict__ cursor,
                            int* __restrict__ srcs, int E) {
    int e = blockIdx.x * blockDim.x + threadIdx.x;
    if (e < E) {
        int d = dst[e];
        int pos = rowptr[d] + atomicAdd(&cursor[d], 1);
        srcs[pos] = src[e];
    }
}

// ---------------- compute ----------------

// Y[M,64] = (X[M,K] @ W[K,64]); optional row-scale by dis[row]. One wave per row.
template<int K, bool SCALE>
__global__ void gemm_kernel(const float* __restrict__ X, const float* __restrict__ W,
                            const float* __restrict__ dis, float* __restrict__ Y, int M) {
    __shared__ float w[K * 64];
    int tid = threadIdx.x;
    for (int i = tid; i < K * 64; i += THREADS) w[i] = W[i];
    __syncthreads();
    int row = blockIdx.x * 4 + (tid >> 6);
    int col = tid & 63;
    if (row >= M) return;
    const float* xr = X + (size_t)row * K;
    float acc = 0.f;
    #pragma unroll
    for (int k = 0; k < K; ++k) acc = fmaf(xr[k], w[k * 64 + col], acc);
    if (SCALE) acc *= dis[row];
    Y[(size_t)row * 64 + col] = acc;
}

// out[d] = relu( dis[d] * (hpre[d] + sum_{s in nbr(d)} hpre[s]) + b )
// hpre is already scaled by dis[src]. One wave per node, lane = feature.
__global__ void pull_kernel(const float* __restrict__ hpre, const int* __restrict__ rowptr,
                            const int* __restrict__ srcs, const float* __restrict__ dis,
                            const float* __restrict__ b, float* __restrict__ out, int N) {
    int tid = threadIdx.x;
    int node = blockIdx.x * 4 + (tid >> 6);
    if (node >= N) return;
    int lane = tid & 63;
    float acc = hpre[(size_t)node * 64 + lane];  // self loop
    int i = rowptr[node], end = rowptr[node + 1];
    for (; i + 4 <= end; i += 4) {
        int s0 = srcs[i], s1 = srcs[i + 1], s2 = srcs[i + 2], s3 = srcs[i + 3];
        float v0 = hpre[(size_t)s0 * 64 + lane];
        float v1 = hpre[(size_t)s1 * 64 + lane];
        float v2 = hpre[(size_t)s2 * 64 + lane];
        float v3 = hpre[(size_t)s3 * 64 + lane];
        acc += v0 + v1 + v2 + v3;
    }
    for (; i < end; ++i) acc += hpre[(size_t)srcs[i] * 64 + lane];
    float o = acc * dis[node] + b[lane];
    out[(size_t)node * 64 + lane] = o > 0.f ? o : 0.f;
}

// ---------------- fallback (atomic push) ----------------

__global__ void degf_kernel(const int* __restrict__ dst, float* __restrict__ deg, int E) {
    int e = blockIdx.x * blockDim.x + threadIdx.x;
    if (e < E) atomicAdd(&deg[dst[e]], 1.0f);
}
__global__ void rsqrtf_kernel(float* deg, int N) {
    int i = blockIdx.x * blockDim.x + threadIdx.x;
    if (i < N) deg[i] = rsqrtf(deg[i] + 1.0f);
}
__global__ void scatter_kernel(const float* __restrict__ h, const int* __restrict__ src,
                               const int* __restrict__ dst, const float* __restrict__ dis,
                               float* __restrict__ agg, int E, int N) {
    long long idx = (long long)blockIdx.x * blockDim.x + threadIdx.x;
    int e = (int)(idx >> 6);
    int f = (int)(idx & 63);
    if (e >= E + N) return;
    int s, d;
    if (e < E) { s = src[e]; d = dst[e]; } else { s = e - E; d = s; }
    float norm = dis[s] * dis[d];
    atomicAdd(&agg[(size_t)d * 64 + f], h[(size_t)s * 64 + f] * norm);
}
__global__ void bias_relu_kernel(float* __restrict__ buf, const float* __restrict__ b,
                                 long long total) {
    long long i = (long long)blockIdx.x * blockDim.x + threadIdx.x;
    if (i < total) {
        float v = buf[i] + b[(int)(i & 63)];
        buf[i] = v > 0.f ? v : 0.f;
    }
}

// ---------------- head ----------------

__global__ void head_kernel(const float* __restrict__ h, const int* __restrict__ pairs,
                            const float* __restrict__ Wh, const float* __restrict__ bh,
                            float* __restrict__ out, int P) {
    long long idx = (long long)blockIdx.x * blockDim.x + threadIdx.x;
    int p = (int)(idx >> 6);
    int lane = threadIdx.x & 63;
    if (p >= P) return;
    int p0 = pairs[2 * (size_t)p];
    int p1 = pairs[2 * (size_t)p + 1];
    float v = h[(size_t)p0 * 64 + lane] * Wh[lane]
            + h[(size_t)p1 * 64 + lane] * Wh[64 + lane];
    #pragma unroll
    for (int off = 32; off > 0; off >>= 1) v += __shfl_down(v, off);
    if (lane == 0) out[p] = v + bh[0];
}

extern "C" void kernel_launch(void* const* d_in, const int* in_sizes, int n_in,
                              void* d_out, int out_size, void* d_ws, size_t ws_size,
                              hipStream_t stream) {
    const float* x     = (const float*)d_in[0];
    const int*   ei    = (const int*)d_in[1];   // [2,E]: row0=src, row1=dst
    const int*   pairs = (const int*)d_in[3];   // [P,2]
    const float* W1    = (const float*)d_in[4];
    const float* b1    = (const float*)d_in[5];
    const float* W2    = (const float*)d_in[6];
    const float* b2    = (const float*)d_in[7];
    const float* Wh    = (const float*)d_in[8];
    const float* bh    = (const float*)d_in[9];

    const int N = in_sizes[0] / 128;
    const int E = in_sizes[1] / 2;
    const int P = in_sizes[3] / 2;
    const int* srcArr = ei;
    const int* dstArr = ei + E;

    const size_t feat_total = (size_t)N * 64;
    const int nbScan = (N + 1023) / 1024;

    auto align512 = [](size_t v) { return (v + 511) & ~(size_t)511; };

    char* ws = (char*)d_ws;
    size_t off = 0;
    float* dis    = (float*)(ws + off); off += align512((size_t)N * 4);
    int*   cnt    = (int*)  (ws + off); off += align512((size_t)N * 4);
    int*   rowptr = (int*)  (ws + off); off += align512(((size_t)N + 1) * 4);
    int*   bsum   = (int*)  (ws + off); off += align512((size_t)nbScan * 4);
    int*   srcs   = (int*)  (ws + off); off += align512((size_t)E * 4);
    float* bufA   = (float*)(ws + off); off += align512(feat_total * 4);
    float* bufB   = (float*)(ws + off); off += align512(feat_total * 4);
    const bool csr_ok = (off <= ws_size) && (nbScan <= 1024);

    if (csr_ok) {
        // ---- CSR build (by dst) ----
        hipMemsetAsync(cnt, 0, (size_t)N * 4, stream);
        hist_kernel<<<(E + THREADS - 1) / THREADS, THREADS, 0, stream>>>(dstArr, cnt, E);
        dis_kernel<<<(N + THREADS - 1) / THREADS, THREADS, 0, stream>>>(cnt, dis, N);
        scan_block_kernel<<<nbScan, 1024, 0, stream>>>(cnt, rowptr, bsum, N);
        scan_partials_kernel<<<1, 1024, 0, stream>>>(bsum, nbScan);
        scan_add_kernel<<<(N + THREADS - 1) / THREADS, THREADS, 0, stream>>>(rowptr, bsum, N);
        hipMemsetAsync(cnt, 0, (size_t)N * 4, stream);
        fill_kernel<<<(E + THREADS - 1) / THREADS, THREADS, 0, stream>>>(
            srcArr, dstArr, rowptr, cnt, srcs, E);

        // ---- layer 1: hpre = (x@W1)*dis ; bufB = relu(dis*(pull)+b1) ----
        gemm_kernel<128, true><<<(N + 3) / 4, THREADS, 0, stream>>>(x, W1, dis, bufA, N);
        pull_kernel<<<(N + 3) / 4, THREADS, 0, stream>>>(bufA, rowptr, srcs, dis, b1, bufB, N);

        // ---- layer 2 ----
        gemm_kernel<64, true><<<(N + 3) / 4, THREADS, 0, stream>>>(bufB, W2, dis, bufA, N);
        pull_kernel<<<(N + 3) / 4, THREADS, 0, stream>>>(bufA, rowptr, srcs, dis, b2, bufB, N);

        // ---- head ----
        head_kernel<<<(unsigned)(((size_t)P * 64 + THREADS - 1) / THREADS), THREADS, 0, stream>>>(
            bufB, pairs, Wh, bh, (float*)d_out, P);
    } else {
        // ---- fallback: atomic push path (round-1 proven) ----
        size_t o2 = 0;
        float* deg  = (float*)(ws + o2); o2 += align512((size_t)N * 4);
        float* bA   = (float*)(ws + o2); o2 += align512(feat_total * 4);
        float* bB   = (float*)(ws + o2);
        const size_t edge_threads = (size_t)(E + N) * 64;

        hipMemsetAsync(deg, 0, (size_t)N * 4, stream);
        degf_kernel<<<(E + THREADS - 1) / THREADS, THREADS, 0, stream>>>(dstArr, deg, E);
        rsqrtf_kernel<<<(N + THREADS - 1) / THREADS, THREADS, 0, stream>>>(deg, N);

        gemm_kernel<128, false><<<(N + 3) / 4, THREADS, 0, stream>>>(x, W1, deg, bA, N);
        hipMemsetAsync(bB, 0, feat_total * 4, stream);
        scatter_kernel<<<(unsigned)((edge_threads + THREADS - 1) / THREADS), THREADS, 0, stream>>>(
            bA, srcArr, dstArr, deg, bB, E, N);
        bias_relu_kernel<<<(unsigned)((feat_total + THREADS - 1) / THREADS), THREADS, 0, stream>>>(
            bB, b1, (long long)feat_total);

        gemm_kernel<64, false><<<(N + 3) / 4, THREADS, 0, stream>>>(bB, W2, deg, bA, N);
        hipMemsetAsync(bB, 0, feat_total * 4, stream);
        scatter_kernel<<<(unsigned)((edge_threads + THREADS - 1) / THREADS), THREADS, 0, stream>>>(
            bA, srcArr, dstArr, deg, bB, E, N);
        bias_relu_kernel<<<(unsigned)((feat_total + THREADS - 1) / THREADS), THREADS, 0, stream>>>(
            bB, b2, (long long)feat_total);

        head_kernel<<<(unsigned)(((size_t)P * 64 + THREADS - 1) / THREADS), THREADS, 0, stream>>>(
            bB, pairs, Wh, bh, (float*)d_out, P);
    }
}

// Round 3
// 462.239 us; speedup vs baseline: 2.4098x; 1.2551x over previous
//
#include <hip/hip_runtime.h>

#define THREADS 256

// ---------------- CSR build ----------------

__global__ void hist_kernel(const int* __restrict__ dst, int* __restrict__ cnt, int E) {
    int e = blockIdx.x * blockDim.x + threadIdx.x;
    if (e < E) atomicAdd(&cnt[dst[e]], 1);
}

__global__ void dis_kernel(const int* __restrict__ cnt, float* __restrict__ dis, int N) {
    int i = blockIdx.x * blockDim.x + threadIdx.x;
    if (i < N) dis[i] = rsqrtf((float)cnt[i] + 1.0f);  // +1 self-loop
}

// block-local inclusive scan of cnt -> rowptr[i+1]; block totals -> bsum[b]
__global__ void scan_block_kernel(const int* __restrict__ cnt, int* __restrict__ rowptr,
                                  int* __restrict__ bsum, int N) {
    __shared__ int sh[1024];
    int t = threadIdx.x;
    int i = blockIdx.x * 1024 + t;
    sh[t] = (i < N) ? cnt[i] : 0;
    __syncthreads();
    for (int off = 1; off < 1024; off <<= 1) {
        int add = (t >= off) ? sh[t - off] : 0;
        __syncthreads();
        sh[t] += add;
        __syncthreads();
    }
    if (i < N) rowptr[i + 1] = sh[t];
    if (t == 1023) bsum[blockIdx.x] = sh[t];
}

// single-block exclusive scan of bsum (nb <= 1024)
__global__ void scan_partials_kernel(int* __restrict__ bsum, int nb) {
    __shared__ int sh[1024];
    int t = threadIdx.x;
    int v = (t < nb) ? bsum[t] : 0;
    sh[t] = v;
    __syncthreads();
    for (int off = 1; off < 1024; off <<= 1) {
        int add = (t >= off) ? sh[t - off] : 0;
        __syncthreads();
        sh[t] += add;
        __syncthreads();
    }
    if (t < nb) bsum[t] = sh[t] - v;  // exclusive
}

__global__ void scan_add_kernel(int* __restrict__ rowptr, const int* __restrict__ bsum, int N) {
    int i = blockIdx.x * blockDim.x + threadIdx.x;
    if (i < N) {
        rowptr[i + 1] += bsum[i >> 10];
        if (i == 0) rowptr[0] = 0;
    }
}

__global__ void fill_kernel(const int* __restrict__ src, const int* __restrict__ dst,
                            const int* __restrict__ rowptr, int* __restrict__ cursor,
                            int* __restrict__ srcs, int E) {
    int e = blockIdx.x * blockDim.x + threadIdx.x;
    if (e < E) {
        int d = dst[e];
        int pos = rowptr[d] + atomicAdd(&cursor[d], 1);
        srcs[pos] = src[e];
    }
}

// ---------------- tiled GEMM ----------------
// Y[M,64] = X[M,K] @ W[K,64], optional row-scale by dis[row].
// Block: 256 threads -> 64x64 output tile, thread computes 4x4 register tile.
// Xs staged transposed [k][row] with row-pitch 68 (16B-aligned, bank-friendly).
template<int K, bool SCALE>
__global__ __launch_bounds__(256) void gemm_tiled(const float* __restrict__ X,
                                                  const float* __restrict__ W,
                                                  const float* __restrict__ dis,
                                                  float* __restrict__ Y, int M) {
    __shared__ float Ws[K * 64];
    __shared__ float Xs[32 * 68];
    const int t = threadIdx.x;

    // stage all of W: [K][64] row-major, contiguous float4 copy
    for (int i = t; i < K * 16; i += THREADS)
        ((float4*)Ws)[i] = ((const float4*)W)[i];

    const int r0 = blockIdx.x * 64;
    const int wave = t >> 6;
    const int lane = t & 63;
    const int tr = lane & 15;               // row group: rows tr*4..tr*4+3
    const int tc = (lane >> 4) + wave * 4;  // col group: cols tc*4..tc*4+3

    float acc[4][4] = {};

    for (int kc = 0; kc < K; kc += 32) {
        __syncthreads();  // protect Xs from previous chunk's readers (and order W stage)
        // stage X[r0..r0+63][kc..kc+31] -> Xs[k][row] (transposed)
        #pragma unroll
        for (int i = t; i < 512; i += THREADS) {
            int row = i >> 3;
            int kq = i & 7;
            int gr = r0 + row;
            if (gr >= M) gr = M - 1;
            float4 v = *(const float4*)(X + (size_t)gr * K + kc + kq * 4);
            Xs[(kq * 4 + 0) * 68 + row] = v.x;
            Xs[(kq * 4 + 1) * 68 + row] = v.y;
            Xs[(kq * 4 + 2) * 68 + row] = v.z;
            Xs[(kq * 4 + 3) * 68 + row] = v.w;
        }
        __syncthreads();
        #pragma unroll
        for (int kk = 0; kk < 32; ++kk) {
            float4 xv = *(const float4*)(Xs + kk * 68 + tr * 4);
            float4 wv = *(const float4*)(Ws + (kc + kk) * 64 + tc * 4);
            acc[0][0] = fmaf(xv.x, wv.x, acc[0][0]);
            acc[0][1] = fmaf(xv.x, wv.y, acc[0][1]);
            acc[0][2] = fmaf(xv.x, wv.z, acc[0][2]);
            acc[0][3] = fmaf(xv.x, wv.w, acc[0][3]);
            acc[1][0] = fmaf(xv.y, wv.x, acc[1][0]);
            acc[1][1] = fmaf(xv.y, wv.y, acc[1][1]);
            acc[1][2] = fmaf(xv.y, wv.z, acc[1][2]);
            acc[1][3] = fmaf(xv.y, wv.w, acc[1][3]);
            acc[2][0] = fmaf(xv.z, wv.x, acc[2][0]);
            acc[2][1] = fmaf(xv.z, wv.y, acc[2][1]);
            acc[2][2] = fmaf(xv.z, wv.z, acc[2][2]);
            acc[2][3] = fmaf(xv.z, wv.w, acc[2][3]);
            acc[3][0] = fmaf(xv.w, wv.x, acc[3][0]);
            acc[3][1] = fmaf(xv.w, wv.y, acc[3][1]);
            acc[3][2] = fmaf(xv.w, wv.z, acc[3][2]);
            acc[3][3] = fmaf(xv.w, wv.w, acc[3][3]);
        }
    }

    #pragma unroll
    for (int i = 0; i < 4; ++i) {
        int row = r0 + tr * 4 + i;
        if (row < M) {
            float s = SCALE ? dis[row] : 1.0f;
            float4 st = make_float4(acc[i][0] * s, acc[i][1] * s, acc[i][2] * s, acc[i][3] * s);
            *(float4*)(Y + (size_t)row * 64 + tc * 4) = st;
        }
    }
}

// ---------------- pull aggregate ----------------
// out[d] = relu( dis[d] * (hpre[d] + sum_{s in nbr(d)} hpre[s]) + b )
// hpre is already scaled by dis[src]. One wave per node, lane = feature.
__global__ void pull_kernel(const float* __restrict__ hpre, const int* __restrict__ rowptr,
                            const int* __restrict__ srcs, const float* __restrict__ dis,
                            const float* __restrict__ b, float* __restrict__ out, int N) {
    int tid = threadIdx.x;
    int node = blockIdx.x * 4 + (tid >> 6);
    if (node >= N) return;
    int lane = tid & 63;
    float acc = hpre[(size_t)node * 64 + lane];  // self loop
    int i = rowptr[node], end = rowptr[node + 1];
    for (; i + 4 <= end; i += 4) {
        int s0 = srcs[i], s1 = srcs[i + 1], s2 = srcs[i + 2], s3 = srcs[i + 3];
        float v0 = hpre[(size_t)s0 * 64 + lane];
        float v1 = hpre[(size_t)s1 * 64 + lane];
        float v2 = hpre[(size_t)s2 * 64 + lane];
        float v3 = hpre[(size_t)s3 * 64 + lane];
        acc += v0 + v1 + v2 + v3;
    }
    for (; i < end; ++i) acc += hpre[(size_t)srcs[i] * 64 + lane];
    float o = acc * dis[node] + b[lane];
    out[(size_t)node * 64 + lane] = o > 0.f ? o : 0.f;
}

// ---------------- head ----------------

__global__ void head_kernel(const float* __restrict__ h, const int* __restrict__ pairs,
                            const float* __restrict__ Wh, const float* __restrict__ bh,
                            float* __restrict__ out, int P) {
    long long idx = (long long)blockIdx.x * blockDim.x + threadIdx.x;
    int p = (int)(idx >> 6);
    int lane = threadIdx.x & 63;
    if (p >= P) return;
    int p0 = pairs[2 * (size_t)p];
    int p1 = pairs[2 * (size_t)p + 1];
    float v = h[(size_t)p0 * 64 + lane] * Wh[lane]
            + h[(size_t)p1 * 64 + lane] * Wh[64 + lane];
    #pragma unroll
    for (int off = 32; off > 0; off >>= 1) v += __shfl_down(v, off);
    if (lane == 0) out[p] = v + bh[0];
}

// ---------------- fallback (atomic push) ----------------

__global__ void degf_kernel(const int* __restrict__ dst, float* __restrict__ deg, int E) {
    int e = blockIdx.x * blockDim.x + threadIdx.x;
    if (e < E) atomicAdd(&deg[dst[e]], 1.0f);
}
__global__ void rsqrtf_kernel(float* deg, int N) {
    int i = blockIdx.x * blockDim.x + threadIdx.x;
    if (i < N) deg[i] = rsqrtf(deg[i] + 1.0f);
}
__global__ void scatter_kernel(const float* __restrict__ h, const int* __restrict__ src,
                               const int* __restrict__ dst, const float* __restrict__ dis,
                               float* __restrict__ agg, int E, int N) {
    long long idx = (long long)blockIdx.x * blockDim.x + threadIdx.x;
    int e = (int)(idx >> 6);
    int f = (int)(idx & 63);
    if (e >= E + N) return;
    int s, d;
    if (e < E) { s = src[e]; d = dst[e]; } else { s = e - E; d = s; }
    float norm = dis[s] * dis[d];
    atomicAdd(&agg[(size_t)d * 64 + f], h[(size_t)s * 64 + f] * norm);
}
__global__ void bias_relu_kernel(float* __restrict__ buf, const float* __restrict__ b,
                                 long long total) {
    long long i = (long long)blockIdx.x * blockDim.x + threadIdx.x;
    if (i < total) {
        float v = buf[i] + b[(int)(i & 63)];
        buf[i] = v > 0.f ? v : 0.f;
    }
}

extern "C" void kernel_launch(void* const* d_in, const int* in_sizes, int n_in,
                              void* d_out, int out_size, void* d_ws, size_t ws_size,
                              hipStream_t stream) {
    const float* x     = (const float*)d_in[0];
    const int*   ei    = (const int*)d_in[1];   // [2,E]: row0=src, row1=dst
    const int*   pairs = (const int*)d_in[3];   // [P,2]
    const float* W1    = (const float*)d_in[4];
    const float* b1    = (const float*)d_in[5];
    const float* W2    = (const float*)d_in[6];
    const float* b2    = (const float*)d_in[7];
    const float* Wh    = (const float*)d_in[8];
    const float* bh    = (const float*)d_in[9];

    const int N = in_sizes[0] / 128;
    const int E = in_sizes[1] / 2;
    const int P = in_sizes[3] / 2;
    const int* srcArr = ei;
    const int* dstArr = ei + E;

    const size_t feat_total = (size_t)N * 64;
    const int nbScan = (N + 1023) / 1024;
    const int gemm_blocks = (N + 63) / 64;

    auto align512 = [](size_t v) { return (v + 511) & ~(size_t)511; };

    char* ws = (char*)d_ws;
    size_t off = 0;
    float* dis    = (float*)(ws + off); off += align512((size_t)N * 4);
    int*   cnt    = (int*)  (ws + off); off += align512((size_t)N * 4);
    int*   rowptr = (int*)  (ws + off); off += align512(((size_t)N + 1) * 4);
    int*   bsum   = (int*)  (ws + off); off += align512((size_t)nbScan * 4);
    int*   srcs   = (int*)  (ws + off); off += align512((size_t)E * 4);
    float* bufA   = (float*)(ws + off); off += align512(feat_total * 4);
    float* bufB   = (float*)(ws + off); off += align512(feat_total * 4);
    const bool csr_ok = (off <= ws_size) && (nbScan <= 1024);

    if (csr_ok) {
        // ---- CSR build (by dst) ----
        hipMemsetAsync(cnt, 0, (size_t)N * 4, stream);
        hist_kernel<<<(E + THREADS - 1) / THREADS, THREADS, 0, stream>>>(dstArr, cnt, E);
        dis_kernel<<<(N + THREADS - 1) / THREADS, THREADS, 0, stream>>>(cnt, dis, N);
        scan_block_kernel<<<nbScan, 1024, 0, stream>>>(cnt, rowptr, bsum, N);
        scan_partials_kernel<<<1, 1024, 0, stream>>>(bsum, nbScan);
        scan_add_kernel<<<(N + THREADS - 1) / THREADS, THREADS, 0, stream>>>(rowptr, bsum, N);
        hipMemsetAsync(cnt, 0, (size_t)N * 4, stream);
        fill_kernel<<<(E + THREADS - 1) / THREADS, THREADS, 0, stream>>>(
            srcArr, dstArr, rowptr, cnt, srcs, E);

        // ---- layer 1: hpre = (x@W1)*dis ; bufB = relu(dis*(pull)+b1) ----
        gemm_tiled<128, true><<<gemm_blocks, THREADS, 0, stream>>>(x, W1, dis, bufA, N);
        pull_kernel<<<(N + 3) / 4, THREADS, 0, stream>>>(bufA, rowptr, srcs, dis, b1, bufB, N);

        // ---- layer 2 ----
        gemm_tiled<64, true><<<gemm_blocks, THREADS, 0, stream>>>(bufB, W2, dis, bufA, N);
        pull_kernel<<<(N + 3) / 4, THREADS, 0, stream>>>(bufA, rowptr, srcs, dis, b2, bufB, N);

        // ---- head ----
        head_kernel<<<(unsigned)(((size_t)P * 64 + THREADS - 1) / THREADS), THREADS, 0, stream>>>(
            bufB, pairs, Wh, bh, (float*)d_out, P);
    } else {
        // ---- fallback: atomic push path ----
        size_t o2 = 0;
        float* deg  = (float*)(ws + o2); o2 += align512((size_t)N * 4);
        float* bA   = (float*)(ws + o2); o2 += align512(feat_total * 4);
        float* bB   = (float*)(ws + o2);
        const size_t edge_threads = (size_t)(E + N) * 64;

        hipMemsetAsync(deg, 0, (size_t)N * 4, stream);
        degf_kernel<<<(E + THREADS - 1) / THREADS, THREADS, 0, stream>>>(dstArr, deg, E);
        rsqrtf_kernel<<<(N + THREADS - 1) / THREADS, THREADS, 0, stream>>>(deg, N);

        gemm_tiled<128, false><<<gemm_blocks, THREADS, 0, stream>>>(x, W1, deg, bA, N);
        hipMemsetAsync(bB, 0, feat_total * 4, stream);
        scatter_kernel<<<(unsigned)((edge_threads + THREADS - 1) / THREADS), THREADS, 0, stream>>>(
            bA, srcArr, dstArr, deg, bB, E, N);
        bias_relu_kernel<<<(unsigned)((feat_total + THREADS - 1) / THREADS), THREADS, 0, stream>>>(
            bB, b1, (long long)feat_total);

        gemm_tiled<64, false><<<gemm_blocks, THREADS, 0, stream>>>(bB, W2, deg, bA, N);
        hipMemsetAsync(bB, 0, feat_total * 4, stream);
        scatter_kernel<<<(unsigned)((edge_threads + THREADS - 1) / THREADS), THREADS, 0, stream>>>(
            bA, srcArr, dstArr, deg, bB, E, N);
        bias_relu_kernel<<<(unsigned)((feat_total + THREADS - 1) / THREADS), THREADS, 0, stream>>>(
            bB, b2, (long long)feat_total);

        head_kernel<<<(unsigned)(((size_t)P * 64 + THREADS - 1) / THREADS), THREADS, 0, stream>>>(
            bB, pairs, Wh, bh, (float*)d_out, P);
    }
}